// Round 7
// baseline (655.344 us; speedup 1.0000x reference)
//
#include <hip/hip_runtime.h>
#include <cmath>

typedef __bf16 bf16_t;
typedef __bf16 bf16x8 __attribute__((ext_vector_type(8)));
typedef __bf16 bf16x4 __attribute__((ext_vector_type(4)));
typedef float f32x4 __attribute__((ext_vector_type(4)));

#define DEV_INLINE __device__ __forceinline__

DEV_INLINE void gload_lds16(const void* g, void* l) {
  __builtin_amdgcn_global_load_lds(
      (const __attribute__((address_space(1))) void*)g,
      (__attribute__((address_space(3))) void*)l, 16, 0, 0);
}

// tanh-form GELU (max dev from exact-erf GELU ~3e-4; cheap: 1 exp + 1 rcp)
DEV_INLINE float gelu_f(float v) {
  const float u = v * (0.7978845608f + 0.0356774081f * v * v);
  const float e = __expf(2.f * u);
  const float th = 1.f - 2.f / (e + 1.f);
  return 0.5f * v * (1.f + th);
}

// ---------------------------------------------------------------------------
// gemm256: C = A[M][lda] * B^T (B stored [N][ldb]) + bias, fused epilogue.
// 256x256 tile, BK=64, 512 threads = 8 waves (2m x 4n), wave tile 128x64
// (8x4 frags of 16x16). 2-phase LDS double buffer (128 KiB): STAGE(next)
// issued BEFORE compute; single __syncthreads per k-iter drains it.
// 64 MFMA per wave per barrier (4x the 128² kernel's quantum).
// Swizzle: intra-row byte ^= ((row&7)<<4) on BOTH stage source and ds_read
// (involution; rows pair 2-way per bank-quad = conflict-free).
// EPI: 0 fp32, 1 bf16, 2 bf16*scale, 3 bf16 gelu, 5 merged-QKV split.
// ---------------------------------------------------------------------------
template<int EPI, bool HAS_BIAS>
__global__ __launch_bounds__(512, 1)
void gemm256(const bf16_t* __restrict__ A, const bf16_t* __restrict__ B,
             const float* __restrict__ bias, void* __restrict__ C,
             bf16_t* __restrict__ vTaux,
             int M, int N, int K, int lda, int ldb, int ldc,
             long sA, long sB, long sC, float scale)
{
  __shared__ alignas(16) bf16_t As[2][16384];   // [256][64] per buffer
  __shared__ alignas(16) bf16_t Bs[2][16384];
  const int b = blockIdx.z;
  A += (long)b * sA;
  B += (long)b * sB;
  const int t  = threadIdx.x;   // 0..511
  const int l  = t & 63;
  const int w  = t >> 6;        // 0..7
  const int wm = w >> 2;        // 0..1  (m half)
  const int wn = w & 3;         // 0..3  (n quarter)
  const int m0 = blockIdx.y * 256;
  const int n0 = blockIdx.x * 256;

  // staging: load j covers row j*64 + (t>>3), 16B chunk (t&7) of the 128-B row,
  // source col-byte XOR-swizzled, LDS dest linear (both-sides rule).
  const int srow  = t >> 3;                       // 0..63
  const int scolb = ((t & 7) * 16) ^ ((srow & 7) << 4);
  const bf16_t* gA = A + (long)(m0 + srow) * lda + (scolb >> 1);
  const bf16_t* gB = B + (long)(n0 + srow) * ldb + (scolb >> 1);

  // fragment read offsets (elements), swizzled per row; ks = k-subtile (0/1)
  const int fr = l & 15;
  const int kq = l >> 4;          // 0..3
  int offA[8][2], offB[4][2];
#pragma unroll
  for (int mi = 0; mi < 8; mi++) {
    const int row = wm * 128 + mi * 16 + fr;
    const int swz = (row & 7) << 4;
#pragma unroll
    for (int ks = 0; ks < 2; ks++)
      offA[mi][ks] = row * 64 + (((ks * 64 + kq * 16) ^ swz) >> 1);
  }
#pragma unroll
  for (int ni = 0; ni < 4; ni++) {
    const int row = wn * 64 + ni * 16 + fr;
    const int swz = (row & 7) << 4;
#pragma unroll
    for (int ks = 0; ks < 2; ks++)
      offB[ni][ks] = row * 64 + (((ks * 64 + kq * 16) ^ swz) >> 1);
  }

#define STAGE256(kt, q) do {                                          \
    const long ko_ = (long)(kt) * 64;                                 \
    gload_lds16(gA + ko_,                    &As[q][t * 8]);          \
    gload_lds16(gA + 64  * (long)lda + ko_,  &As[q][4096  + t * 8]);  \
    gload_lds16(gA + 128 * (long)lda + ko_,  &As[q][8192  + t * 8]);  \
    gload_lds16(gA + 192 * (long)lda + ko_,  &As[q][12288 + t * 8]);  \
    gload_lds16(gB + ko_,                    &Bs[q][t * 8]);          \
    gload_lds16(gB + 64  * (long)ldb + ko_,  &Bs[q][4096  + t * 8]);  \
    gload_lds16(gB + 128 * (long)ldb + ko_,  &Bs[q][8192  + t * 8]);  \
    gload_lds16(gB + 192 * (long)ldb + ko_,  &Bs[q][12288 + t * 8]);  \
  } while (0)

  f32x4 acc[8][4] = {};

  const int NT = K >> 6;
  STAGE256(0, 0);
  __syncthreads();

  int cur = 0;
  for (int kt = 0; kt < NT; ++kt) {
    if (kt + 1 < NT) STAGE256(kt + 1, cur ^ 1);   // overlap with compute
#pragma unroll
    for (int ks = 0; ks < 2; ks++) {
      bf16x8 af[8], bf[4];
#pragma unroll
      for (int mi = 0; mi < 8; mi++)
        af[mi] = *(const bf16x8*)&As[cur][offA[mi][ks]];
#pragma unroll
      for (int ni = 0; ni < 4; ni++)
        bf[ni] = *(const bf16x8*)&Bs[cur][offB[ni][ks]];
#pragma unroll
      for (int mi = 0; mi < 8; mi++)
#pragma unroll
        for (int ni = 0; ni < 4; ni++)
          acc[mi][ni] = __builtin_amdgcn_mfma_f32_16x16x32_bf16(
              af[mi], bf[ni], acc[mi][ni], 0, 0, 0);
    }
    __syncthreads();            // drains prefetch (vmcnt0) + retires reads
    cur ^= 1;
  }
#undef STAGE256

  // C/D layout: col = lane&15, row = 4*(lane>>4) + reg
  const long cb = (long)b * sC;
  const int rbase = m0 + wm * 128 + kq * 4;
#pragma unroll
  for (int mi = 0; mi < 8; mi++) {
    const int row0 = rbase + mi * 16;
#pragma unroll
    for (int ni = 0; ni < 4; ni++) {
      const int c = n0 + wn * 64 + ni * 16 + fr;
      float bias_v = 0.f;
      if constexpr (HAS_BIAS) bias_v = bias[c];
      float vals[4];
#pragma unroll
      for (int r = 0; r < 4; r++) {
        float v = acc[mi][ni][r] + bias_v;
        if constexpr (EPI == 2) v *= scale;
        if constexpr (EPI == 3) v = gelu_f(v);
        vals[r] = v;
      }
      if constexpr (EPI == 5) {
        if (c < 1024) {          // block-uniform (n0 is 256-aligned)
#pragma unroll
          for (int r = 0; r < 4; r++)
            ((bf16_t*)C)[(long)(row0 + r) * ldc + c] = (bf16_t)vals[r];
        } else {
          const int bb = row0 >> 11;
          const int n  = row0 & 2047;
          bf16x4 pk = { (bf16_t)vals[0], (bf16_t)vals[1],
                        (bf16_t)vals[2], (bf16_t)vals[3] };
          *(bf16x4*)&vTaux[(long)bb * (512 * 2048) + (long)(c - 1024) * 2048 + n] = pk;
        }
      } else {
#pragma unroll
        for (int r = 0; r < 4; r++) {
          const long idx = cb + (long)(row0 + r) * ldc + c;
          if constexpr (EPI == 0) ((float*)C)[idx] = vals[r];
          else                    ((bf16_t*)C)[idx] = (bf16_t)vals[r];
        }
      }
    }
  }
}

// ---------------------------------------------------------------------------
// gemm_bt: 128x128 tile, BK=32, 4 waves, 3-buffer ring, counted vmcnt,
// one barrier per k-iter. (Kept for PV, whose N=512 grid needs 128² blocks.)
// ---------------------------------------------------------------------------
template<int EPI, bool HAS_BIAS>
__global__ __launch_bounds__(256, 2)
void gemm_bt(const bf16_t* __restrict__ A, const bf16_t* __restrict__ B,
             const float* __restrict__ bias, void* __restrict__ C,
             bf16_t* __restrict__ vTaux,
             int M, int N, int K, int lda, int ldb, int ldc,
             long sA, long sB, long sC, float scale)
{
  __shared__ alignas(16) bf16_t lds[3][2][4096];
  const int b = blockIdx.z;
  A += (long)b * sA;
  B += (long)b * sB;
  const int t  = threadIdx.x;
  const int l  = t & 63;
  const int w  = t >> 6;
  const int wr = (w >> 1) * 64;
  const int wc = (w & 1) * 64;
  const int m0 = blockIdx.y * 128;
  const int n0 = blockIdx.x * 128;

  const int r0 = t >> 2;
  const int r1 = r0 + 64;
  const int wb = (t & 3) * 16;
  const int cb0 = wb ^ (((r0 >> 1) & 3) << 4);
  const int cb1 = wb ^ (((r1 >> 1) & 3) << 4);
  const bf16_t* gA0 = A + (long)(m0 + r0) * lda + (cb0 >> 1);
  const bf16_t* gA1 = A + (long)(m0 + r1) * lda + (cb1 >> 1);
  const bf16_t* gB0 = B + (long)(n0 + r0) * ldb + (cb0 >> 1);
  const bf16_t* gB1 = B + (long)(n0 + r1) * ldb + (cb1 >> 1);

#define STAGE(kt, q) do {                                   \
    const long kofs_ = (long)(kt) * 32;                     \
    gload_lds16(gA0 + kofs_, &lds[q][0][t * 8]);            \
    gload_lds16(gA1 + kofs_, &lds[q][0][2048 + t * 8]);     \
    gload_lds16(gB0 + kofs_, &lds[q][1][t * 8]);            \
    gload_lds16(gB1 + kofs_, &lds[q][1][2048 + t * 8]);     \
  } while (0)

  const int fr  = l & 15;
  const int kkb = (l >> 4) * 16;
  int offA[4], offB[4];
#pragma unroll
  for (int mi = 0; mi < 4; mi++) {
    const int row = wr + mi * 16 + fr;
    offA[mi] = row * 32 + ((kkb ^ (((row >> 1) & 3) << 4)) >> 1);
  }
#pragma unroll
  for (int ni = 0; ni < 4; ni++) {
    const int row = wc + ni * 16 + fr;
    offB[ni] = row * 32 + ((kkb ^ (((row >> 1) & 3) << 4)) >> 1);
  }

  f32x4 acc[4][4] = {};

  const int NT = K >> 5;
  STAGE(0, 0);
  STAGE(1, 1);

  int q = 0;
  for (int kt = 0; kt < NT; ++kt) {
    if (kt < NT - 1) asm volatile("s_waitcnt vmcnt(4)" ::: "memory");
    else             asm volatile("s_waitcnt vmcnt(0)" ::: "memory");
    __builtin_amdgcn_sched_barrier(0);
    __builtin_amdgcn_s_barrier();

    if (kt + 2 < NT) {
      int qs = q + 2; if (qs >= 3) qs -= 3;
      STAGE(kt + 2, qs);
    }

    bf16x8 af[4], bfr[4];
#pragma unroll
    for (int mi = 0; mi < 4; mi++)
      af[mi] = *(const bf16x8*)&lds[q][0][offA[mi]];
#pragma unroll
    for (int ni = 0; ni < 4; ni++)
      bfr[ni] = *(const bf16x8*)&lds[q][1][offB[ni]];
#pragma unroll
    for (int mi = 0; mi < 4; mi++)
#pragma unroll
      for (int ni = 0; ni < 4; ni++)
        acc[mi][ni] = __builtin_amdgcn_mfma_f32_16x16x32_bf16(
            af[mi], bfr[ni], acc[mi][ni], 0, 0, 0);

    if (++q == 3) q = 0;
  }
#undef STAGE

  const long cb = (long)b * sC;
  const int rbase = m0 + wr + (l >> 4) * 4;
#pragma unroll
  for (int mi = 0; mi < 4; mi++) {
    const int row0 = rbase + mi * 16;
#pragma unroll
    for (int ni = 0; ni < 4; ni++) {
      const int c = n0 + wc + ni * 16 + fr;
      float bias_v = 0.f;
      if constexpr (HAS_BIAS) bias_v = bias[c];
      float vals[4];
#pragma unroll
      for (int r = 0; r < 4; r++) {
        float v = acc[mi][ni][r] + bias_v;
        if constexpr (EPI == 2) v *= scale;
        if constexpr (EPI == 3) v = gelu_f(v);
        vals[r] = v;
      }
#pragma unroll
      for (int r = 0; r < 4; r++) {
        const long idx = cb + (long)(row0 + r) * ldc + c;
        if constexpr (EPI == 0) ((float*)C)[idx] = vals[r];
        else                    ((bf16_t*)C)[idx] = (bf16_t)vals[r];
      }
    }
  }
}

// ---------------------------------------------------------------------------
__global__ __launch_bounds__(256)
void transpose_cast(const float* __restrict__ in, bf16_t* __restrict__ out,
                    int R, int Cc)
{
  __shared__ float tile[32][33];
  const int c0 = blockIdx.x * 32;
  const int r0 = blockIdx.y * 32;
  const int tx = threadIdx.x & 31;
  const int ty = threadIdx.x >> 5;
#pragma unroll
  for (int i = 0; i < 32; i += 8)
    tile[ty + i][tx] = in[(long)(r0 + ty + i) * Cc + (c0 + tx)];
  __syncthreads();
#pragma unroll
  for (int i = 0; i < 32; i += 8)
    out[(long)(c0 + ty + i) * R + (r0 + tx)] = (bf16_t)tile[tx][ty + i];
}

__global__ __launch_bounds__(256)
void cast_to_bf16(const float* __restrict__ in, bf16_t* __restrict__ out, long n)
{
  const long i = ((long)blockIdx.x * 256 + threadIdx.x) * 4;
  if (i >= n) return;
  const float4 v = *(const float4*)&in[i];
  bf16x4 o = { (bf16_t)v.x, (bf16_t)v.y, (bf16_t)v.z, (bf16_t)v.w };
  *(bf16x4*)&out[i] = o;
}

__global__ __launch_bounds__(256)
void concat_bias(const float* __restrict__ a, const float* __restrict__ b,
                 const float* __restrict__ c, float* __restrict__ o)
{
  const int i = blockIdx.x * 256 + threadIdx.x;
  if (i < 512) o[i] = a[i];
  else if (i < 1024) o[i] = b[i - 512];
  else if (i < 1536) o[i] = c[i - 1024];
}

// ---------------------------------------------------------------------------
__global__ __launch_bounds__(256)
void softmax2048(bf16_t* __restrict__ E)
{
  const long row = blockIdx.x;
  bf16_t* p = E + row * 2048;
  const int t = threadIdx.x;
  bf16x8 xv = *(const bf16x8*)&p[t * 8];
  float v[8];
#pragma unroll
  for (int j = 0; j < 8; j++) v[j] = (float)xv[j];
  float m = v[0];
#pragma unroll
  for (int j = 1; j < 8; j++) m = fmaxf(m, v[j]);
  for (int o = 32; o; o >>= 1) m = fmaxf(m, __shfl_xor(m, o));
  __shared__ float redm[4];
  __shared__ float reds[4];
  if ((t & 63) == 0) redm[t >> 6] = m;
  __syncthreads();
  m = fmaxf(fmaxf(redm[0], redm[1]), fmaxf(redm[2], redm[3]));
  float s = 0.f;
#pragma unroll
  for (int j = 0; j < 8; j++) { v[j] = __expf(v[j] - m); s += v[j]; }
  for (int o = 32; o; o >>= 1) s += __shfl_xor(s, o);
  if ((t & 63) == 0) reds[t >> 6] = s;
  __syncthreads();
  s = reds[0] + reds[1] + reds[2] + reds[3];
  const float inv = 1.f / s;
  bf16x8 ov;
#pragma unroll
  for (int j = 0; j < 8; j++) ov[j] = (bf16_t)(v[j] * inv);
  *(bf16x8*)&p[t * 8] = ov;
}

// ---------------------------------------------------------------------------
template<bool A_BF16, bool EMIT_F32, bool EMIT_BF16>
__global__ __launch_bounds__(128)
void add_ln(const void* __restrict__ xa_, const float* __restrict__ xadd,
            const float* __restrict__ g, const float* __restrict__ be,
            float* __restrict__ y, bf16_t* __restrict__ yb)
{
  const long row = blockIdx.x;
  const int c = threadIdx.x * 4;
  float av[4];
  if constexpr (A_BF16) {
    const bf16_t* xa = (const bf16_t*)xa_;
    bf16x4 a = *(const bf16x4*)&xa[row * 512 + c];
#pragma unroll
    for (int j = 0; j < 4; j++) av[j] = (float)a[j];
  } else {
    const float* xa = (const float*)xa_;
    const float4 a = *(const float4*)&xa[row * 512 + c];
    av[0] = a.x; av[1] = a.y; av[2] = a.z; av[3] = a.w;
  }
  const float4 bb = *(const float4*)&xadd[row * 512 + c];
  float vv[4] = { av[0] + bb.x, av[1] + bb.y, av[2] + bb.z, av[3] + bb.w };
  float s = 0.f, s2 = 0.f;
#pragma unroll
  for (int j = 0; j < 4; j++) { s += vv[j]; s2 += vv[j] * vv[j]; }
  for (int o = 32; o; o >>= 1) { s += __shfl_xor(s, o); s2 += __shfl_xor(s2, o); }
  __shared__ float r0[2], r1[2];
  const int w = threadIdx.x >> 6;
  if ((threadIdx.x & 63) == 0) { r0[w] = s; r1[w] = s2; }
  __syncthreads();
  s = r0[0] + r0[1]; s2 = r1[0] + r1[1];
  const float mu = s * (1.f / 512.f);
  const float var = s2 * (1.f / 512.f) - mu * mu;
  const float rstd = rsqrtf(var + 1e-5f);
  const float4 gg = *(const float4*)&g[c];
  const float4 bev = *(const float4*)&be[c];
  float o0 = (vv[0] - mu) * rstd * gg.x + bev.x;
  float o1 = (vv[1] - mu) * rstd * gg.y + bev.y;
  float o2 = (vv[2] - mu) * rstd * gg.z + bev.z;
  float o3 = (vv[3] - mu) * rstd * gg.w + bev.w;
  if constexpr (EMIT_F32) {
    float4 yo = { o0, o1, o2, o3 };
    *(float4*)&y[row * 512 + c] = yo;
  }
  if constexpr (EMIT_BF16) {
    bf16x4 ob = { (bf16_t)o0, (bf16_t)o1, (bf16_t)o2, (bf16_t)o3 };
    *(bf16x4*)&yb[row * 512 + c] = ob;
  }
}

// ---------------------------------------------------------------------------
extern "C" void kernel_launch(void* const* d_in, const int* in_sizes, int n_in,
                              void* d_out, int out_size, void* d_ws, size_t ws_size,
                              hipStream_t stream)
{
  const float* x   = (const float*)d_in[0];
  const float* wq  = (const float*)d_in[1];
  const float* bq  = (const float*)d_in[2];
  const float* wk  = (const float*)d_in[3];
  const float* bk  = (const float*)d_in[4];
  const float* wv  = (const float*)d_in[5];
  const float* bv  = (const float*)d_in[6];
  const float* wp  = (const float*)d_in[7];
  const float* bp  = (const float*)d_in[8];
  const float* w1  = (const float*)d_in[9];
  const float* b1  = (const float*)d_in[10];
  const float* w2  = (const float*)d_in[11];
  const float* b2  = (const float*)d_in[12];
  const float* g1  = (const float*)d_in[13];
  const float* be1 = (const float*)d_in[14];
  const float* g2  = (const float*)d_in[15];
  const float* be2 = (const float*)d_in[16];

  const long S = 16L * 2048 * 512;   // tokens*D
  const long Mi = 1L << 20;

  const size_t NEED = (size_t)200 * Mi;
  if (ws_size < NEED) return;

  char* wsp = (char*)d_ws;
  bf16_t* wqkvT = (bf16_t*)(wsp + 0);            // [1536][512]
  bf16_t* wpT   = wqkvT + 1536L * 512;           // [512][512]
  bf16_t* w1T   = wpT + 512L * 512;              // [2048][512]
  bf16_t* w2T   = w1T + 2048L * 512;             // [512][2048]
  float*  bqkv  = (float*)(w2T + 512L * 2048);   // [1536]
  bf16_t* xb  = (bf16_t*)(wsp +   8 * Mi);       // 32 MiB
  bf16_t* qkb = (bf16_t*)(wsp +  40 * Mi);       // 64 MiB [32768][1024]
  bf16_t* vT  = (bf16_t*)(wsp + 104 * Mi);       // 32 MiB
  bf16_t* E   = (bf16_t*)(wsp + 136 * Mi);       // 64 MiB
  bf16_t* ob  = xb;                              // PV out
  bf16_t* x1b = qkb;                             // 32 MiB at off 40
  bf16_t* h   = (bf16_t*)(wsp + 72 * Mi);        // 128 MiB [32768][2048]

  // 1. cast x -> bf16
  cast_to_bf16<<<dim3((unsigned)(S / 4 / 256)), 256, 0, stream>>>(x, xb, S);

  // 2. weight transposes + bias concat
  transpose_cast<<<dim3(16, 16), 256, 0, stream>>>(wq, wqkvT,               512, 512);
  transpose_cast<<<dim3(16, 16), 256, 0, stream>>>(wk, wqkvT + 512L * 512,  512, 512);
  transpose_cast<<<dim3(16, 16), 256, 0, stream>>>(wv, wqkvT + 1024L * 512, 512, 512);
  transpose_cast<<<dim3(16, 16), 256, 0, stream>>>(wp, wpT, 512, 512);
  transpose_cast<<<dim3(64, 16), 256, 0, stream>>>(w1, w1T, 512, 2048);
  transpose_cast<<<dim3(16, 64), 256, 0, stream>>>(w2, w2T, 2048, 512);
  concat_bias<<<dim3(6), 256, 0, stream>>>(bq, bk, bv, bqkv);

  // 3. merged QKV GEMM (M=32768, N=1536, K=512), split epilogue
  gemm256<5, true><<<dim3(6, 128, 1), 512, 0, stream>>>(
      xb, wqkvT, bqkv, qkb, vT, 32768, 1536, 512, 512, 512, 1024, 0, 0, 0, 0.f);

  // 4. attention in 2 chunks of 8 batches
  for (int cgrp = 0; cgrp < 2; cgrp++) {
    const long qoff = (long)cgrp * 8 * 2048 * 1024;
    // E = (q k^T) * 1/sqrt(512)  (M=N=2048, K=512, z=8)
    gemm256<2, false><<<dim3(8, 8, 8), 512, 0, stream>>>(
        qkb + qoff, qkb + qoff + 512, nullptr, E, nullptr,
        2048, 2048, 512, 1024, 1024, 2048,
        2048L * 1024, 2048L * 1024, 2048L * 2048, 0.04419417382f);
    // softmax rows
    softmax2048<<<dim3(16384), 256, 0, stream>>>(E);
    // out = P V  (M=2048, N=512, K=2048, z=8) — 128² kernel (grid 512)
    gemm_bt<1, false><<<dim3(4, 16, 8), 256, 0, stream>>>(
        E, vT + (long)cgrp * 8 * 512 * 2048, nullptr,
        ob + (long)cgrp * 8 * 2048 * 512, nullptr,
        2048, 512, 2048, 2048, 2048, 512,
        2048L * 2048, 512L * 2048, 2048L * 512, 0.f);
  }

  // 5. proj -> d_out (fp32 scratch)
  gemm256<0, true><<<dim3(2, 128, 1), 512, 0, stream>>>(
      ob, wpT, bp, (float*)d_out, nullptr,
      32768, 512, 512, 512, 512, 512, 0, 0, 0, 0.f);

  // 6. x1b = bf16( LN(x + proj) )
  add_ln<false, false, true><<<dim3(32768), 128, 0, stream>>>(
      x, (float*)d_out, g1, be1, nullptr, x1b);

  // 7. FF1: h = gelu(x1 w1 + b1)  (M=32768, N=2048, K=512)
  gemm256<3, true><<<dim3(8, 128, 1), 512, 0, stream>>>(
      x1b, w1T, b1, h, nullptr, 32768, 2048, 512, 512, 512, 2048, 0, 0, 0, 0.f);

  // 8. FF2: ff = h w2 + b2 -> d_out (fp32)  (M=32768, N=512, K=2048)
  gemm256<0, true><<<dim3(2, 128, 1), 512, 0, stream>>>(
      h, w2T, b2, (float*)d_out, nullptr,
      32768, 512, 2048, 2048, 2048, 512, 0, 0, 0, 0.f);

  // 9. out = LN(x1 + ff), in place on d_out
  add_ln<true, true, false><<<dim3(32768), 128, 0, stream>>>(
      x1b, (float*)d_out, g2, be2, (float*)d_out, nullptr);
}

// Round 8
// 643.356 us; speedup vs baseline: 1.0186x; 1.0186x over previous
//
#include <hip/hip_runtime.h>
#include <cmath>

typedef __bf16 bf16_t;
typedef __bf16 bf16x8 __attribute__((ext_vector_type(8)));
typedef __bf16 bf16x4 __attribute__((ext_vector_type(4)));
typedef float f32x4 __attribute__((ext_vector_type(4)));

#define DEV_INLINE __device__ __forceinline__

DEV_INLINE void gload_lds16(const void* g, void* l) {
  __builtin_amdgcn_global_load_lds(
      (const __attribute__((address_space(1))) void*)g,
      (__attribute__((address_space(3))) void*)l, 16, 0, 0);
}

// tanh-form GELU (max dev from exact-erf GELU ~3e-4)
DEV_INLINE float gelu_f(float v) {
  const float u = v * (0.7978845608f + 0.0356774081f * v * v);
  const float e = __expf(2.f * u);
  const float th = 1.f - 2.f / (e + 1.f);
  return 0.5f * v * (1.f + th);
}

// ---------------------------------------------------------------------------
// gemm256 — 8-phase counted-vmcnt schedule (T3+T4+T5, m201 template port).
// 256x256 tile, BK=64, 512 threads = 8 waves (2m x 4n), wave tile 128x64.
// LDS: As[2][256][64] + Bs[2][256][64] = 128 KiB; tile kt -> buffer kt&1;
// 2 K-tiles per loop iteration (static buffer indices).
// Per K-tile: 4 quadrant-phases (m-half x n-half), 16 MFMA each:
//   { ds_read subtile ; stage half-tile ; s_barrier ; lgkmcnt(0)+sched_barrier ;
//     setprio(1) 16xMFMA setprio(0) ; s_barrier }
// Stage region-safety (derived from read retirement): B-halves of a buffer are
// free after that buffer's P2-close, A-halves after P3-close. Stages:
//   P3: B(kt+2) both halves | P4: A(kt+2).h0 | P5: A(kt+2).h1
//   P7: B(kt+3) both halves | P8: A(kt+3).h0 | P1(next): A(kt+3).h1
// vmcnt(6) at P4 (gates tile kt+1 reads) and P8 (gates tile kt+2 reads);
// drains to 0 only in the last iteration. Every half staged ~6 phases ahead.
// Swizzle (T2): source col-byte ^ ((row&7)<<4); same XOR on ds_read offsets
// (both-sides involution; measured conflict-free).
// ---------------------------------------------------------------------------
template<int EPI, bool HAS_BIAS>
__global__ __launch_bounds__(512, 1)
void gemm256(const bf16_t* __restrict__ A, const bf16_t* __restrict__ B,
             const float* __restrict__ bias, void* __restrict__ C,
             bf16_t* __restrict__ vTaux,
             int M, int N, int K, int lda, int ldb, int ldc,
             long sA, long sB, long sC, float scale)
{
  __shared__ alignas(16) bf16_t As[2][16384];   // [buf][256*64]
  __shared__ alignas(16) bf16_t Bs[2][16384];
  const int b = blockIdx.z;
  A += (long)b * sA;
  B += (long)b * sB;
  const int t  = threadIdx.x;   // 0..511
  const int l  = t & 63;
  const int w  = t >> 6;        // 0..7
  const int wm = w >> 2;        // 0..1
  const int wn = w & 3;         // 0..3
  const int m0 = blockIdx.y * 256;
  const int n0 = blockIdx.x * 256;

  // staging geometry: row srow(+64j+128h), byte (t&7)*16 pre-swizzled by row&7
  const int srow  = t >> 3;
  const int scolb = ((t & 7) * 16) ^ ((srow & 7) << 4);
  const bf16_t* gA = A + (long)(m0 + srow) * lda + (scolb >> 1);
  const bf16_t* gB = B + (long)(n0 + srow) * ldb + (scolb >> 1);

#define SG_A(q, h, kt) do { const long ko_ = (long)(kt) * 64;                 \
    gload_lds16(gA + (long)((h) * 128) * lda + ko_,                           \
                &As[q][(h) * 8192 + t * 8]);                                  \
    gload_lds16(gA + (long)((h) * 128 + 64) * lda + ko_,                      \
                &As[q][(h) * 8192 + 4096 + t * 8]); } while (0)
#define SG_B(q, h, kt) do { const long ko_ = (long)(kt) * 64;                 \
    gload_lds16(gB + (long)((h) * 128) * ldb + ko_,                           \
                &Bs[q][(h) * 8192 + t * 8]);                                  \
    gload_lds16(gB + (long)((h) * 128 + 64) * ldb + ko_,                      \
                &Bs[q][(h) * 8192 + 4096 + t * 8]); } while (0)

  // fragment read offsets (elements), swizzled per row; ks = k-subtile (0/1)
  const int fr = l & 15;
  const int kq = l >> 4;          // 0..3
  int offA[8][2], offB[4][2];
#pragma unroll
  for (int mi = 0; mi < 8; mi++) {
    const int row = wm * 128 + mi * 16 + fr;
    const int swz = (row & 7) << 4;
#pragma unroll
    for (int ks = 0; ks < 2; ks++)
      offA[mi][ks] = row * 64 + (((ks * 64 + kq * 16) ^ swz) >> 1);
  }
#pragma unroll
  for (int ni = 0; ni < 4; ni++) {
    const int row = wn * 64 + ni * 16 + fr;
    const int swz = (row & 7) << 4;
#pragma unroll
    for (int ks = 0; ks < 2; ks++)
      offB[ni][ks] = row * 64 + (((ks * 64 + kq * 16) ^ swz) >> 1);
  }

#define RD_A(arr, q, mh) do {                                                 \
  _Pragma("unroll") for (int mi2_ = 0; mi2_ < 4; ++mi2_) {                    \
    arr[mi2_][0] = *(const bf16x8*)&As[q][offA[(mh) * 4 + mi2_][0]];          \
    arr[mi2_][1] = *(const bf16x8*)&As[q][offA[(mh) * 4 + mi2_][1]]; } } while (0)
#define RD_B(arr, q, nh) do {                                                 \
  _Pragma("unroll") for (int ni2_ = 0; ni2_ < 2; ++ni2_) {                    \
    arr[ni2_][0] = *(const bf16x8*)&Bs[q][offB[(nh) * 2 + ni2_][0]];          \
    arr[ni2_][1] = *(const bf16x8*)&Bs[q][offB[(nh) * 2 + ni2_][1]]; } } while (0)
#define MM(mh, nh, AA, BB)                                                    \
  _Pragma("unroll") for (int mi2_ = 0; mi2_ < 4; ++mi2_)                      \
  _Pragma("unroll") for (int ni2_ = 0; ni2_ < 2; ++ni2_)                      \
  _Pragma("unroll") for (int ks_ = 0; ks_ < 2; ++ks_)                         \
    acc[(mh) * 4 + mi2_][(nh) * 2 + ni2_] =                                   \
        __builtin_amdgcn_mfma_f32_16x16x32_bf16(                              \
            AA[mi2_][ks_], BB[ni2_][ks_],                                     \
            acc[(mh) * 4 + mi2_][(nh) * 2 + ni2_], 0, 0, 0);

#define BAR()   __builtin_amdgcn_s_barrier()
#define LGKM0() do { asm volatile("s_waitcnt lgkmcnt(0)" ::: "memory");       \
                     __builtin_amdgcn_sched_barrier(0); } while (0)
#define PRIO1() __builtin_amdgcn_s_setprio(1)
#define PRIO0() do { __builtin_amdgcn_s_setprio(0);                           \
                     __builtin_amdgcn_sched_barrier(0); } while (0)

  f32x4 acc[8][4] = {};
  bf16x8 a0[4][2], a1[4][2], b0[2][2], b1[2][2];

  const int NT = K >> 6;        // K-tiles of 64 (even, >=4 for all our shapes)
  const int NITER = NT >> 1;

  // prologue: tile0 full -> buf0; tile1 B both halves + A.h0 -> buf1
  SG_A(0, 0, 0); SG_A(0, 1, 0); SG_B(0, 0, 0); SG_B(0, 1, 0);
  SG_B(1, 0, 1); SG_B(1, 1, 1); SG_A(1, 0, 1);
  asm volatile("s_waitcnt vmcnt(6)" ::: "memory");   // tile0 landed
  __builtin_amdgcn_sched_barrier(0);
  BAR();

#define GEMM256_ITER(LAST, k0) do {                                           \
    /* ---- P1: quadrant (0,0) of tile k0 (buf0) ---- */                      \
    RD_A(a0, 0, 0); RD_B(b0, 0, 0);                                           \
    SG_A(1, 1, (k0) + 1);             /* finish tile k0+1 staging */          \
    BAR(); LGKM0();                                                           \
    PRIO1(); MM(0, 0, a0, b0) PRIO0(); BAR();                                 \
    /* ---- P2: (0,1) ---- */                                                 \
    RD_B(b1, 0, 1);                                                           \
    BAR(); LGKM0();                                                           \
    PRIO1(); MM(0, 1, a0, b1) PRIO0(); BAR();                                 \
    /* ---- P3: (1,0); stage B(k0+2) -> buf0 (B free after P2-close) ---- */  \
    RD_A(a1, 0, 1);                                                           \
    if (!(LAST)) { SG_B(0, 0, (k0) + 2); SG_B(0, 1, (k0) + 2); }              \
    BAR(); LGKM0();                                                           \
    PRIO1(); MM(1, 0, a1, b0) PRIO0(); BAR();                                 \
    /* ---- P4: (1,1); stage A(k0+2).h0; vmcnt gates tile k0+1 ---- */        \
    if (!(LAST)) {                                                            \
      SG_A(0, 0, (k0) + 2);                                                   \
      asm volatile("s_waitcnt vmcnt(6)" ::: "memory");                        \
    } else {                                                                  \
      asm volatile("s_waitcnt vmcnt(0)" ::: "memory");                        \
    }                                                                         \
    __builtin_amdgcn_sched_barrier(0);                                        \
    BAR();                                                                    \
    PRIO1(); MM(1, 1, a1, b1) PRIO0(); BAR();                                 \
    /* ---- P5: (0,0) of tile k0+1 (buf1); stage A(k0+2).h1 ---- */           \
    RD_A(a0, 1, 0); RD_B(b0, 1, 0);                                           \
    if (!(LAST)) SG_A(0, 1, (k0) + 2);                                        \
    BAR(); LGKM0();                                                           \
    PRIO1(); MM(0, 0, a0, b0) PRIO0(); BAR();                                 \
    /* ---- P6: (0,1) ---- */                                                 \
    RD_B(b1, 1, 1);                                                           \
    BAR(); LGKM0();                                                           \
    PRIO1(); MM(0, 1, a0, b1) PRIO0(); BAR();                                 \
    /* ---- P7: (1,0); stage B(k0+3) -> buf1 ---- */                          \
    RD_A(a1, 1, 1);                                                           \
    if (!(LAST)) { SG_B(1, 0, (k0) + 3); SG_B(1, 1, (k0) + 3); }              \
    BAR(); LGKM0();                                                           \
    PRIO1(); MM(1, 0, a1, b0) PRIO0(); BAR();                                 \
    /* ---- P8: (1,1); stage A(k0+3).h0; vmcnt gates tile k0+2 ---- */        \
    if (!(LAST)) {                                                            \
      SG_A(1, 0, (k0) + 3);                                                   \
      asm volatile("s_waitcnt vmcnt(6)" ::: "memory");                        \
      __builtin_amdgcn_sched_barrier(0);                                      \
    }                                                                         \
    BAR();                                                                    \
    PRIO1(); MM(1, 1, a1, b1) PRIO0(); BAR();                                 \
  } while (0)

  for (int tt = 0; tt < NITER - 1; ++tt)
    GEMM256_ITER(0, 2 * tt);
  GEMM256_ITER(1, NT - 2);

#undef GEMM256_ITER
#undef SG_A
#undef SG_B
#undef RD_A
#undef RD_B
#undef MM
#undef BAR
#undef LGKM0
#undef PRIO1
#undef PRIO0

  // C/D layout: col = lane&15, row = 4*(lane>>4) + reg
  const long cb = (long)b * sC;
  const int rbase = m0 + wm * 128 + kq * 4;
#pragma unroll
  for (int mi = 0; mi < 8; mi++) {
    const int row0 = rbase + mi * 16;
#pragma unroll
    for (int ni = 0; ni < 4; ni++) {
      const int c = n0 + wn * 64 + ni * 16 + fr;
      float bias_v = 0.f;
      if constexpr (HAS_BIAS) bias_v = bias[c];
      float vals[4];
#pragma unroll
      for (int r = 0; r < 4; r++) {
        float v = acc[mi][ni][r] + bias_v;
        if constexpr (EPI == 2) v *= scale;
        if constexpr (EPI == 3) v = gelu_f(v);
        vals[r] = v;
      }
      if constexpr (EPI == 5) {
        if (c < 1024) {          // block-uniform (n0 is 256-aligned)
#pragma unroll
          for (int r = 0; r < 4; r++)
            ((bf16_t*)C)[(long)(row0 + r) * ldc + c] = (bf16_t)vals[r];
        } else {
          const int bb = row0 >> 11;
          const int n  = row0 & 2047;
          bf16x4 pk = { (bf16_t)vals[0], (bf16_t)vals[1],
                        (bf16_t)vals[2], (bf16_t)vals[3] };
          *(bf16x4*)&vTaux[(long)bb * (512 * 2048) + (long)(c - 1024) * 2048 + n] = pk;
        }
      } else {
#pragma unroll
        for (int r = 0; r < 4; r++) {
          const long idx = cb + (long)(row0 + r) * ldc + c;
          if constexpr (EPI == 0) ((float*)C)[idx] = vals[r];
          else                    ((bf16_t*)C)[idx] = (bf16_t)vals[r];
        }
      }
    }
  }
}

// ---------------------------------------------------------------------------
// gemm_bt: 128x128 tile, BK=32, 4 waves, 3-buffer ring, counted vmcnt,
// one barrier per k-iter. (Used for PV: N=512 grid needs 128² blocks.)
// ---------------------------------------------------------------------------
template<int EPI, bool HAS_BIAS>
__global__ __launch_bounds__(256, 2)
void gemm_bt(const bf16_t* __restrict__ A, const bf16_t* __restrict__ B,
             const float* __restrict__ bias, void* __restrict__ C,
             bf16_t* __restrict__ vTaux,
             int M, int N, int K, int lda, int ldb, int ldc,
             long sA, long sB, long sC, float scale)
{
  __shared__ alignas(16) bf16_t lds[3][2][4096];
  const int b = blockIdx.z;
  A += (long)b * sA;
  B += (long)b * sB;
  const int t  = threadIdx.x;
  const int l  = t & 63;
  const int w  = t >> 6;
  const int wr = (w >> 1) * 64;
  const int wc = (w & 1) * 64;
  const int m0 = blockIdx.y * 128;
  const int n0 = blockIdx.x * 128;

  const int r0 = t >> 2;
  const int r1 = r0 + 64;
  const int wb = (t & 3) * 16;
  const int cb0 = wb ^ (((r0 >> 1) & 3) << 4);
  const int cb1 = wb ^ (((r1 >> 1) & 3) << 4);
  const bf16_t* gA0 = A + (long)(m0 + r0) * lda + (cb0 >> 1);
  const bf16_t* gA1 = A + (long)(m0 + r1) * lda + (cb1 >> 1);
  const bf16_t* gB0 = B + (long)(n0 + r0) * ldb + (cb0 >> 1);
  const bf16_t* gB1 = B + (long)(n0 + r1) * ldb + (cb1 >> 1);

#define STAGE(kt, q) do {                                   \
    const long kofs_ = (long)(kt) * 32;                     \
    gload_lds16(gA0 + kofs_, &lds[q][0][t * 8]);            \
    gload_lds16(gA1 + kofs_, &lds[q][0][2048 + t * 8]);     \
    gload_lds16(gB0 + kofs_, &lds[q][1][t * 8]);            \
    gload_lds16(gB1 + kofs_, &lds[q][1][2048 + t * 8]);     \
  } while (0)

  const int fr  = l & 15;
  const int kkb = (l >> 4) * 16;
  int offA[4], offB[4];
#pragma unroll
  for (int mi = 0; mi < 4; mi++) {
    const int row = wr + mi * 16 + fr;
    offA[mi] = row * 32 + ((kkb ^ (((row >> 1) & 3) << 4)) >> 1);
  }
#pragma unroll
  for (int ni = 0; ni < 4; ni++) {
    const int row = wc + ni * 16 + fr;
    offB[ni] = row * 32 + ((kkb ^ (((row >> 1) & 3) << 4)) >> 1);
  }

  f32x4 acc[4][4] = {};

  const int NT = K >> 5;
  STAGE(0, 0);
  STAGE(1, 1);

  int q = 0;
  for (int kt = 0; kt < NT; ++kt) {
    if (kt < NT - 1) asm volatile("s_waitcnt vmcnt(4)" ::: "memory");
    else             asm volatile("s_waitcnt vmcnt(0)" ::: "memory");
    __builtin_amdgcn_sched_barrier(0);
    __builtin_amdgcn_s_barrier();

    if (kt + 2 < NT) {
      int qs = q + 2; if (qs >= 3) qs -= 3;
      STAGE(kt + 2, qs);
    }

    bf16x8 af[4], bfr[4];
#pragma unroll
    for (int mi = 0; mi < 4; mi++)
      af[mi] = *(const bf16x8*)&lds[q][0][offA[mi]];
#pragma unroll
    for (int ni = 0; ni < 4; ni++)
      bfr[ni] = *(const bf16x8*)&lds[q][1][offB[ni]];
#pragma unroll
    for (int mi = 0; mi < 4; mi++)
#pragma unroll
      for (int ni = 0; ni < 4; ni++)
        acc[mi][ni] = __builtin_amdgcn_mfma_f32_16x16x32_bf16(
            af[mi], bfr[ni], acc[mi][ni], 0, 0, 0);

    if (++q == 3) q = 0;
  }
#undef STAGE

  const long cb = (long)b * sC;
  const int rbase = m0 + wr + (l >> 4) * 4;
#pragma unroll
  for (int mi = 0; mi < 4; mi++) {
    const int row0 = rbase + mi * 16;
#pragma unroll
    for (int ni = 0; ni < 4; ni++) {
      const int c = n0 + wc + ni * 16 + fr;
      float bias_v = 0.f;
      if constexpr (HAS_BIAS) bias_v = bias[c];
      float vals[4];
#pragma unroll
      for (int r = 0; r < 4; r++) {
        float v = acc[mi][ni][r] + bias_v;
        if constexpr (EPI == 2) v *= scale;
        if constexpr (EPI == 3) v = gelu_f(v);
        vals[r] = v;
      }
#pragma unroll
      for (int r = 0; r < 4; r++) {
        const long idx = cb + (long)(row0 + r) * ldc + c;
        if constexpr (EPI == 0) ((float*)C)[idx] = vals[r];
        else                    ((bf16_t*)C)[idx] = (bf16_t)vals[r];
      }
    }
  }
}

// ---------------------------------------------------------------------------
__global__ __launch_bounds__(256)
void transpose_cast(const float* __restrict__ in, bf16_t* __restrict__ out,
                    int R, int Cc)
{
  __shared__ float tile[32][33];
  const int c0 = blockIdx.x * 32;
  const int r0 = blockIdx.y * 32;
  const int tx = threadIdx.x & 31;
  const int ty = threadIdx.x >> 5;
#pragma unroll
  for (int i = 0; i < 32; i += 8)
    tile[ty + i][tx] = in[(long)(r0 + ty + i) * Cc + (c0 + tx)];
  __syncthreads();
#pragma unroll
  for (int i = 0; i < 32; i += 8)
    out[(long)(c0 + ty + i) * R + (r0 + tx)] = (bf16_t)tile[tx][ty + i];
}

__global__ __launch_bounds__(256)
void cast_to_bf16(const float* __restrict__ in, bf16_t* __restrict__ out, long n)
{
  const long i = ((long)blockIdx.x * 256 + threadIdx.x) * 4;
  if (i >= n) return;
  const float4 v = *(const float4*)&in[i];
  bf16x4 o = { (bf16_t)v.x, (bf16_t)v.y, (bf16_t)v.z, (bf16_t)v.w };
  *(bf16x4*)&out[i] = o;
}

__global__ __launch_bounds__(256)
void concat_bias(const float* __restrict__ a, const float* __restrict__ b,
                 const float* __restrict__ c, float* __restrict__ o)
{
  const int i = blockIdx.x * 256 + threadIdx.x;
  if (i < 512) o[i] = a[i];
  else if (i < 1024) o[i] = b[i - 512];
  else if (i < 1536) o[i] = c[i - 1024];
}

// ---------------------------------------------------------------------------
__global__ __launch_bounds__(256)
void softmax2048(bf16_t* __restrict__ E)
{
  const long row = blockIdx.x;
  bf16_t* p = E + row * 2048;
  const int t = threadIdx.x;
  bf16x8 xv = *(const bf16x8*)&p[t * 8];
  float v[8];
#pragma unroll
  for (int j = 0; j < 8; j++) v[j] = (float)xv[j];
  float m = v[0];
#pragma unroll
  for (int j = 1; j < 8; j++) m = fmaxf(m, v[j]);
  for (int o = 32; o; o >>= 1) m = fmaxf(m, __shfl_xor(m, o));
  __shared__ float redm[4];
  __shared__ float reds[4];
  if ((t & 63) == 0) redm[t >> 6] = m;
  __syncthreads();
  m = fmaxf(fmaxf(redm[0], redm[1]), fmaxf(redm[2], redm[3]));
  float s = 0.f;
#pragma unroll
  for (int j = 0; j < 8; j++) { v[j] = __expf(v[j] - m); s += v[j]; }
  for (int o = 32; o; o >>= 1) s += __shfl_xor(s, o);
  if ((t & 63) == 0) reds[t >> 6] = s;
  __syncthreads();
  s = reds[0] + reds[1] + reds[2] + reds[3];
  const float inv = 1.f / s;
  bf16x8 ov;
#pragma unroll
  for (int j = 0; j < 8; j++) ov[j] = (bf16_t)(v[j] * inv);
  *(bf16x8*)&p[t * 8] = ov;
}

// ---------------------------------------------------------------------------
template<bool A_BF16, bool EMIT_F32, bool EMIT_BF16>
__global__ __launch_bounds__(128)
void add_ln(const void* __restrict__ xa_, const float* __restrict__ xadd,
            const float* __restrict__ g, const float* __restrict__ be,
            float* __restrict__ y, bf16_t* __restrict__ yb)
{
  const long row = blockIdx.x;
  const int c = threadIdx.x * 4;
  float av[4];
  if constexpr (A_BF16) {
    const bf16_t* xa = (const bf16_t*)xa_;
    bf16x4 a = *(const bf16x4*)&xa[row * 512 + c];
#pragma unroll
    for (int j = 0; j < 4; j++) av[j] = (float)a[j];
  } else {
    const float* xa = (const float*)xa_;
    const float4 a = *(const float4*)&xa[row * 512 + c];
    av[0] = a.x; av[1] = a.y; av[2] = a.z; av[3] = a.w;
  }
  const float4 bb = *(const float4*)&xadd[row * 512 + c];
  float vv[4] = { av[0] + bb.x, av[1] + bb.y, av[2] + bb.z, av[3] + bb.w };
  float s = 0.f, s2 = 0.f;
#pragma unroll
  for (int j = 0; j < 4; j++) { s += vv[j]; s2 += vv[j] * vv[j]; }
  for (int o = 32; o; o >>= 1) { s += __shfl_xor(s, o); s2 += __shfl_xor(s2, o); }
  __shared__ float r0[2], r1[2];
  const int w = threadIdx.x >> 6;
  if ((threadIdx.x & 63) == 0) { r0[w] = s; r1[w] = s2; }
  __syncthreads();
  s = r0[0] + r0[1]; s2 = r1[0] + r1[1];
  const float mu = s * (1.f / 512.f);
  const float var = s2 * (1.f / 512.f) - mu * mu;
  const float rstd = rsqrtf(var + 1e-5f);
  const float4 gg = *(const float4*)&g[c];
  const float4 bev = *(const float4*)&be[c];
  float o0 = (vv[0] - mu) * rstd * gg.x + bev.x;
  float o1 = (vv[1] - mu) * rstd * gg.y + bev.y;
  float o2 = (vv[2] - mu) * rstd * gg.z + bev.z;
  float o3 = (vv[3] - mu) * rstd * gg.w + bev.w;
  if constexpr (EMIT_F32) {
    float4 yo = { o0, o1, o2, o3 };
    *(float4*)&y[row * 512 + c] = yo;
  }
  if constexpr (EMIT_BF16) {
    bf16x4 ob = { (bf16_t)o0, (bf16_t)o1, (bf16_t)o2, (bf16_t)o3 };
    *(bf16x4*)&yb[row * 512 + c] = ob;
  }
}

// ---------------------------------------------------------------------------
extern "C" void kernel_launch(void* const* d_in, const int* in_sizes, int n_in,
                              void* d_out, int out_size, void* d_ws, size_t ws_size,
                              hipStream_t stream)
{
  const float* x   = (const float*)d_in[0];
  const float* wq  = (const float*)d_in[1];
  const float* bq  = (const float*)d_in[2];
  const float* wk  = (const float*)d_in[3];
  const float* bk  = (const float*)d_in[4];
  const float* wv  = (const float*)d_in[5];
  const float* bv  = (const float*)d_in[6];
  const float* wp  = (const float*)d_in[7];
  const float* bp  = (const float*)d_in[8];
  const float* w1  = (const float*)d_in[9];
  const float* b1  = (const float*)d_in[10];
  const float* w2  = (const float*)d_in[11];
  const float* b2  = (const float*)d_in[12];
  const float* g1  = (const float*)d_in[13];
  const float* be1 = (const float*)d_in[14];
  const float* g2  = (const float*)d_in[15];
  const float* be2 = (const float*)d_in[16];

  const long S = 16L * 2048 * 512;   // tokens*D
  const long Mi = 1L << 20;

  const size_t NEED = (size_t)200 * Mi;
  if (ws_size < NEED) return;

  char* wsp = (char*)d_ws;
  bf16_t* wqkvT = (bf16_t*)(wsp + 0);            // [1536][512]
  bf16_t* wpT   = wqkvT + 1536L * 512;           // [512][512]
  bf16_t* w1T   = wpT + 512L * 512;              // [2048][512]
  bf16_t* w2T   = w1T + 2048L * 512;             // [512][2048]
  float*  bqkv  = (float*)(w2T + 512L * 2048);   // [1536]
  bf16_t* xb  = (bf16_t*)(wsp +   8 * Mi);       // 32 MiB
  bf16_t* qkb = (bf16_t*)(wsp +  40 * Mi);       // 64 MiB [32768][1024]
  bf16_t* vT  = (bf16_t*)(wsp + 104 * Mi);       // 32 MiB
  bf16_t* E   = (bf16_t*)(wsp + 136 * Mi);       // 64 MiB
  bf16_t* ob  = xb;                              // PV out
  bf16_t* x1b = qkb;                             // 32 MiB at off 40
  bf16_t* h   = (bf16_t*)(wsp + 72 * Mi);        // 128 MiB [32768][2048]

  // 1. cast x -> bf16
  cast_to_bf16<<<dim3((unsigned)(S / 4 / 256)), 256, 0, stream>>>(x, xb, S);

  // 2. weight transposes + bias concat
  transpose_cast<<<dim3(16, 16), 256, 0, stream>>>(wq, wqkvT,               512, 512);
  transpose_cast<<<dim3(16, 16), 256, 0, stream>>>(wk, wqkvT + 512L * 512,  512, 512);
  transpose_cast<<<dim3(16, 16), 256, 0, stream>>>(wv, wqkvT + 1024L * 512, 512, 512);
  transpose_cast<<<dim3(16, 16), 256, 0, stream>>>(wp, wpT, 512, 512);
  transpose_cast<<<dim3(64, 16), 256, 0, stream>>>(w1, w1T, 512, 2048);
  transpose_cast<<<dim3(16, 64), 256, 0, stream>>>(w2, w2T, 2048, 512);
  concat_bias<<<dim3(6), 256, 0, stream>>>(bq, bk, bv, bqkv);

  // 3. merged QKV GEMM (M=32768, N=1536, K=512), split epilogue
  gemm256<5, true><<<dim3(6, 128, 1), 512, 0, stream>>>(
      xb, wqkvT, bqkv, qkb, vT, 32768, 1536, 512, 512, 512, 1024, 0, 0, 0, 0.f);

  // 4. attention in 2 chunks of 8 batches
  for (int cgrp = 0; cgrp < 2; cgrp++) {
    const long qoff = (long)cgrp * 8 * 2048 * 1024;
    // E = (q k^T) * 1/sqrt(512)  (M=N=2048, K=512, z=8)
    gemm256<2, false><<<dim3(8, 8, 8), 512, 0, stream>>>(
        qkb + qoff, qkb + qoff + 512, nullptr, E, nullptr,
        2048, 2048, 512, 1024, 1024, 2048,
        2048L * 1024, 2048L * 1024, 2048L * 2048, 0.04419417382f);
    // softmax rows
    softmax2048<<<dim3(16384), 256, 0, stream>>>(E);
    // out = P V  (M=2048, N=512, K=2048, z=8) — 128² ring kernel (grid 512)
    gemm_bt<1, false><<<dim3(4, 16, 8), 256, 0, stream>>>(
        E, vT + (long)cgrp * 8 * 512 * 2048, nullptr,
        ob + (long)cgrp * 8 * 2048 * 512, nullptr,
        2048, 512, 2048, 2048, 2048, 512,
        2048L * 2048, 512L * 2048, 2048L * 512, 0.f);
  }

  // 5. proj -> d_out (fp32 scratch)
  gemm256<0, true><<<dim3(2, 128, 1), 512, 0, stream>>>(
      ob, wpT, bp, (float*)d_out, nullptr,
      32768, 512, 512, 512, 512, 512, 0, 0, 0, 0.f);

  // 6. x1b = bf16( LN(x + proj) )
  add_ln<false, false, true><<<dim3(32768), 128, 0, stream>>>(
      x, (float*)d_out, g1, be1, nullptr, x1b);

  // 7. FF1: h = gelu(x1 w1 + b1)  (M=32768, N=2048, K=512)
  gemm256<3, true><<<dim3(8, 128, 1), 512, 0, stream>>>(
      x1b, w1T, b1, h, nullptr, 32768, 2048, 512, 512, 512, 2048, 0, 0, 0, 0.f);

  // 8. FF2: ff = h w2 + b2 -> d_out (fp32)  (M=32768, N=512, K=2048)
  gemm256<0, true><<<dim3(2, 128, 1), 512, 0, stream>>>(
      h, w2T, b2, (float*)d_out, nullptr,
      32768, 512, 2048, 2048, 2048, 512, 0, 0, 0, 0.f);

  // 9. out = LN(x1 + ff), in place on d_out
  add_ln<true, true, false><<<dim3(32768), 128, 0, stream>>>(
      x1b, (float*)d_out, g2, be2, (float*)d_out, nullptr);
}

// Round 9
// 622.601 us; speedup vs baseline: 1.0526x; 1.0333x over previous
//
#include <hip/hip_runtime.h>
#include <cmath>

typedef __bf16 bf16_t;
typedef __bf16 bf16x8 __attribute__((ext_vector_type(8)));
typedef __bf16 bf16x4 __attribute__((ext_vector_type(4)));
typedef float f32x4 __attribute__((ext_vector_type(4)));

#define DEV_INLINE __device__ __forceinline__

DEV_INLINE void gload_lds16(const void* g, void* l) {
  __builtin_amdgcn_global_load_lds(
      (const __attribute__((address_space(1))) void*)g,
      (__attribute__((address_space(3))) void*)l, 16, 0, 0);
}

// tanh-form GELU (max dev from exact-erf GELU ~3e-4)
DEV_INLINE float gelu_f(float v) {
  const float u = v * (0.7978845608f + 0.0356774081f * v * v);
  const float e = __expf(2.f * u);
  const float th = 1.f - 2.f / (e + 1.f);
  return 0.5f * v * (1.f + th);
}

// ---------------------------------------------------------------------------
// gemm_bt: C = A[M][.lda] * B^T (B stored [N][.ldb]) + bias, fused epilogue.
// EPI: 0 = fp32 out, 1 = bf16 out, 2 = bf16 out *scale (no bias), 3 = bf16
//      gelu(out), 5 = merged-QKV split: cols<1024 -> bf16 C[row][c] (ldc),
//      cols>=1024 -> V written TRANSPOSED per batch into vTaux[b][c-1024][n].
// 128x128 tile, BK=32, 256 threads = 4 waves (2x2), wave tile 64x64.
// Pipeline: 3-buffer LDS ring (48 KiB -> 3 blocks/CU), lookahead 2, one raw
// s_barrier per k-iter, counted vmcnt(4) steady state (round-6 best config).
// T1: XCD-aware block swizzle — id -> (id&7)*(nwg/8) + id>>3 (nwg%8==0 for
// every launch in this file) so each XCD's L2 owns a contiguous tile chunk;
// same-A-row blocks stop re-fetching A through 8 separate L2s.
// T2 swizzle: byte ^= ((row>>1)&3)<<4 on BOTH stage-source and ds_read.
// ---------------------------------------------------------------------------
template<int EPI, bool HAS_BIAS>
__global__ __launch_bounds__(256, 2)
void gemm_bt(const bf16_t* __restrict__ A, const bf16_t* __restrict__ B,
             const float* __restrict__ bias, void* __restrict__ C,
             bf16_t* __restrict__ vTaux,
             int M, int N, int K, int lda, int ldb, int ldc,
             long sA, long sB, long sC, float scale)
{
  __shared__ alignas(16) bf16_t lds[3][2][4096];
  const int b = blockIdx.z;
  A += (long)b * sA;
  B += (long)b * sB;
  const int t  = threadIdx.x;
  const int l  = t & 63;
  const int w  = t >> 6;
  const int wr = (w >> 1) * 64;
  const int wc = (w & 1) * 64;

  // T1 XCD swizzle (per z-slice): nwg%8==0 for all launches in this file
  const int gx  = gridDim.x;
  const int nwg = gx * gridDim.y;
  int id = blockIdx.y * gx + blockIdx.x;
  id = (id & 7) * (nwg >> 3) + (id >> 3);
  const int m0 = (id / gx) * 128;
  const int n0 = (id % gx) * 128;

  // staging geometry: thread t covers rows r0=t/4, r1=r0+64; byte (t&3)*16.
  // Source col-byte XOR-swizzled; LDS dest linear (rule #21 both-sides).
  const int r0 = t >> 2;
  const int r1 = r0 + 64;
  const int wb = (t & 3) * 16;
  const int cb0 = wb ^ (((r0 >> 1) & 3) << 4);
  const int cb1 = wb ^ (((r1 >> 1) & 3) << 4);
  const bf16_t* gA0 = A + (long)(m0 + r0) * lda + (cb0 >> 1);
  const bf16_t* gA1 = A + (long)(m0 + r1) * lda + (cb1 >> 1);
  const bf16_t* gB0 = B + (long)(n0 + r0) * ldb + (cb0 >> 1);
  const bf16_t* gB1 = B + (long)(n0 + r1) * ldb + (cb1 >> 1);

#define STAGE(kt, q) do {                                   \
    const long kofs_ = (long)(kt) * 32;                     \
    gload_lds16(gA0 + kofs_, &lds[q][0][t * 8]);            \
    gload_lds16(gA1 + kofs_, &lds[q][0][2048 + t * 8]);     \
    gload_lds16(gB0 + kofs_, &lds[q][1][t * 8]);            \
    gload_lds16(gB1 + kofs_, &lds[q][1][2048 + t * 8]);     \
  } while (0)

  const int fr  = l & 15;
  const int kkb = (l >> 4) * 16;
  int offA[4], offB[4];
#pragma unroll
  for (int mi = 0; mi < 4; mi++) {
    const int row = wr + mi * 16 + fr;
    offA[mi] = row * 32 + ((kkb ^ (((row >> 1) & 3) << 4)) >> 1);
  }
#pragma unroll
  for (int ni = 0; ni < 4; ni++) {
    const int row = wc + ni * 16 + fr;
    offB[ni] = row * 32 + ((kkb ^ (((row >> 1) & 3) << 4)) >> 1);
  }

  f32x4 acc[4][4] = {};

  const int NT = K >> 5;
  STAGE(0, 0);
  STAGE(1, 1);

  int q = 0;
  for (int kt = 0; kt < NT; ++kt) {
    if (kt < NT - 1) asm volatile("s_waitcnt vmcnt(4)" ::: "memory");
    else             asm volatile("s_waitcnt vmcnt(0)" ::: "memory");
    __builtin_amdgcn_sched_barrier(0);
    __builtin_amdgcn_s_barrier();

    if (kt + 2 < NT) {
      int qs = q + 2; if (qs >= 3) qs -= 3;
      STAGE(kt + 2, qs);
    }

    bf16x8 af[4], bfr[4];
#pragma unroll
    for (int mi = 0; mi < 4; mi++)
      af[mi] = *(const bf16x8*)&lds[q][0][offA[mi]];
#pragma unroll
    for (int ni = 0; ni < 4; ni++)
      bfr[ni] = *(const bf16x8*)&lds[q][1][offB[ni]];
#pragma unroll
    for (int mi = 0; mi < 4; mi++)
#pragma unroll
      for (int ni = 0; ni < 4; ni++)
        acc[mi][ni] = __builtin_amdgcn_mfma_f32_16x16x32_bf16(
            af[mi], bfr[ni], acc[mi][ni], 0, 0, 0);

    if (++q == 3) q = 0;
  }
#undef STAGE

  // C/D layout: col = lane&15, row = 4*(lane>>4) + reg
  const long cb = (long)b * sC;
  const int rbase = m0 + wr + (l >> 4) * 4;
#pragma unroll
  for (int mi = 0; mi < 4; mi++) {
    const int row0 = rbase + mi * 16;
#pragma unroll
    for (int ni = 0; ni < 4; ni++) {
      const int c = n0 + wc + ni * 16 + fr;
      float bias_v = 0.f;
      if constexpr (HAS_BIAS) bias_v = bias[c];
      float vals[4];
#pragma unroll
      for (int r = 0; r < 4; r++) {
        float v = acc[mi][ni][r] + bias_v;
        if constexpr (EPI == 2) v *= scale;
        if constexpr (EPI == 3) v = gelu_f(v);
        vals[r] = v;
      }
      if constexpr (EPI == 5) {
        if (c < 1024) {           // block-uniform branch (n0 128-aligned)
#pragma unroll
          for (int r = 0; r < 4; r++)
            ((bf16_t*)C)[(long)(row0 + r) * ldc + c] = (bf16_t)vals[r];
        } else {
          const int bb = row0 >> 11;        // batch
          const int n  = row0 & 2047;       // token within batch (mult of 4)
          bf16x4 pk = { (bf16_t)vals[0], (bf16_t)vals[1],
                        (bf16_t)vals[2], (bf16_t)vals[3] };
          *(bf16x4*)&vTaux[(long)bb * (512 * 2048) + (long)(c - 1024) * 2048 + n] = pk;
        }
      } else {
#pragma unroll
        for (int r = 0; r < 4; r++) {
          const long idx = cb + (long)(row0 + r) * ldc + c;
          if constexpr (EPI == 0) ((float*)C)[idx] = vals[r];
          else                    ((bf16_t*)C)[idx] = (bf16_t)vals[r];
        }
      }
    }
  }
}

// ---------------------------------------------------------------------------
__global__ __launch_bounds__(256)
void transpose_cast(const float* __restrict__ in, bf16_t* __restrict__ out,
                    int R, int Cc)
{
  __shared__ float tile[32][33];
  const int c0 = blockIdx.x * 32;
  const int r0 = blockIdx.y * 32;
  const int tx = threadIdx.x & 31;
  const int ty = threadIdx.x >> 5;
#pragma unroll
  for (int i = 0; i < 32; i += 8)
    tile[ty + i][tx] = in[(long)(r0 + ty + i) * Cc + (c0 + tx)];
  __syncthreads();
#pragma unroll
  for (int i = 0; i < 32; i += 8)
    out[(long)(c0 + ty + i) * R + (r0 + tx)] = (bf16_t)tile[tx][ty + i];
}

__global__ __launch_bounds__(256)
void cast_to_bf16(const float* __restrict__ in, bf16_t* __restrict__ out, long n)
{
  const long i = ((long)blockIdx.x * 256 + threadIdx.x) * 4;
  if (i >= n) return;
  const float4 v = *(const float4*)&in[i];
  bf16x4 o = { (bf16_t)v.x, (bf16_t)v.y, (bf16_t)v.z, (bf16_t)v.w };
  *(bf16x4*)&out[i] = o;
}

__global__ __launch_bounds__(256)
void concat_bias(const float* __restrict__ a, const float* __restrict__ b,
                 const float* __restrict__ c, float* __restrict__ o)
{
  const int i = blockIdx.x * 256 + threadIdx.x;
  if (i < 512) o[i] = a[i];
  else if (i < 1024) o[i] = b[i - 512];
  else if (i < 1536) o[i] = c[i - 1024];
}

// ---------------------------------------------------------------------------
__global__ __launch_bounds__(256)
void softmax2048(bf16_t* __restrict__ E)
{
  const long row = blockIdx.x;
  bf16_t* p = E + row * 2048;
  const int t = threadIdx.x;
  bf16x8 xv = *(const bf16x8*)&p[t * 8];
  float v[8];
#pragma unroll
  for (int j = 0; j < 8; j++) v[j] = (float)xv[j];
  float m = v[0];
#pragma unroll
  for (int j = 1; j < 8; j++) m = fmaxf(m, v[j]);
  for (int o = 32; o; o >>= 1) m = fmaxf(m, __shfl_xor(m, o));
  __shared__ float redm[4];
  __shared__ float reds[4];
  if ((t & 63) == 0) redm[t >> 6] = m;
  __syncthreads();
  m = fmaxf(fmaxf(redm[0], redm[1]), fmaxf(redm[2], redm[3]));
  float s = 0.f;
#pragma unroll
  for (int j = 0; j < 8; j++) { v[j] = __expf(v[j] - m); s += v[j]; }
  for (int o = 32; o; o >>= 1) s += __shfl_xor(s, o);
  if ((t & 63) == 0) reds[t >> 6] = s;
  __syncthreads();
  s = reds[0] + reds[1] + reds[2] + reds[3];
  const float inv = 1.f / s;
  bf16x8 ov;
#pragma unroll
  for (int j = 0; j < 8; j++) ov[j] = (bf16_t)(v[j] * inv);
  *(bf16x8*)&p[t * 8] = ov;
}

// ---------------------------------------------------------------------------
template<bool A_BF16, bool EMIT_F32, bool EMIT_BF16>
__global__ __launch_bounds__(128)
void add_ln(const void* __restrict__ xa_, const float* __restrict__ xadd,
            const float* __restrict__ g, const float* __restrict__ be,
            float* __restrict__ y, bf16_t* __restrict__ yb)
{
  const long row = blockIdx.x;
  const int c = threadIdx.x * 4;
  float av[4];
  if constexpr (A_BF16) {
    const bf16_t* xa = (const bf16_t*)xa_;
    bf16x4 a = *(const bf16x4*)&xa[row * 512 + c];
#pragma unroll
    for (int j = 0; j < 4; j++) av[j] = (float)a[j];
  } else {
    const float* xa = (const float*)xa_;
    const float4 a = *(const float4*)&xa[row * 512 + c];
    av[0] = a.x; av[1] = a.y; av[2] = a.z; av[3] = a.w;
  }
  const float4 bb = *(const float4*)&xadd[row * 512 + c];
  float vv[4] = { av[0] + bb.x, av[1] + bb.y, av[2] + bb.z, av[3] + bb.w };
  float s = 0.f, s2 = 0.f;
#pragma unroll
  for (int j = 0; j < 4; j++) { s += vv[j]; s2 += vv[j] * vv[j]; }
  for (int o = 32; o; o >>= 1) { s += __shfl_xor(s, o); s2 += __shfl_xor(s2, o); }
  __shared__ float r0[2], r1[2];
  const int w = threadIdx.x >> 6;
  if ((threadIdx.x & 63) == 0) { r0[w] = s; r1[w] = s2; }
  __syncthreads();
  s = r0[0] + r0[1]; s2 = r1[0] + r1[1];
  const float mu = s * (1.f / 512.f);
  const float var = s2 * (1.f / 512.f) - mu * mu;
  const float rstd = rsqrtf(var + 1e-5f);
  const float4 gg = *(const float4*)&g[c];
  const float4 bev = *(const float4*)&be[c];
  float o0 = (vv[0] - mu) * rstd * gg.x + bev.x;
  float o1 = (vv[1] - mu) * rstd * gg.y + bev.y;
  float o2 = (vv[2] - mu) * rstd * gg.z + bev.z;
  float o3 = (vv[3] - mu) * rstd * gg.w + bev.w;
  if constexpr (EMIT_F32) {
    float4 yo = { o0, o1, o2, o3 };
    *(float4*)&y[row * 512 + c] = yo;
  }
  if constexpr (EMIT_BF16) {
    bf16x4 ob = { (bf16_t)o0, (bf16_t)o1, (bf16_t)o2, (bf16_t)o3 };
    *(bf16x4*)&yb[row * 512 + c] = ob;
  }
}

// ---------------------------------------------------------------------------
extern "C" void kernel_launch(void* const* d_in, const int* in_sizes, int n_in,
                              void* d_out, int out_size, void* d_ws, size_t ws_size,
                              hipStream_t stream)
{
  const float* x   = (const float*)d_in[0];
  const float* wq  = (const float*)d_in[1];
  const float* bq  = (const float*)d_in[2];
  const float* wk  = (const float*)d_in[3];
  const float* bk  = (const float*)d_in[4];
  const float* wv  = (const float*)d_in[5];
  const float* bv  = (const float*)d_in[6];
  const float* wp  = (const float*)d_in[7];
  const float* bp  = (const float*)d_in[8];
  const float* w1  = (const float*)d_in[9];
  const float* b1  = (const float*)d_in[10];
  const float* w2  = (const float*)d_in[11];
  const float* b2  = (const float*)d_in[12];
  const float* g1  = (const float*)d_in[13];
  const float* be1 = (const float*)d_in[14];
  const float* g2  = (const float*)d_in[15];
  const float* be2 = (const float*)d_in[16];

  const long S = 16L * 2048 * 512;   // tokens*D
  const long Mi = 1L << 20;

  const size_t NEED = (size_t)200 * Mi;
  if (ws_size < NEED) return;

  char* wsp = (char*)d_ws;
  bf16_t* wqkvT = (bf16_t*)(wsp + 0);            // [1536][512]
  bf16_t* wpT   = wqkvT + 1536L * 512;           // [512][512]
  bf16_t* w1T   = wpT + 512L * 512;              // [2048][512]
  bf16_t* w2T   = w1T + 2048L * 512;             // [512][2048]
  float*  bqkv  = (float*)(w2T + 512L * 2048);   // [1536]
  bf16_t* xb  = (bf16_t*)(wsp +   8 * Mi);       // 32 MiB
  bf16_t* qkb = (bf16_t*)(wsp +  40 * Mi);       // 64 MiB [32768][1024]
  bf16_t* vT  = (bf16_t*)(wsp + 104 * Mi);       // 32 MiB
  bf16_t* E   = (bf16_t*)(wsp + 136 * Mi);       // 64 MiB
  bf16_t* ob  = xb;                              // PV out
  bf16_t* x1b = qkb;                             // 32 MiB at off 40
  bf16_t* h   = (bf16_t*)(wsp + 72 * Mi);        // 128 MiB [32768][2048]

  // 1. cast x -> bf16
  cast_to_bf16<<<dim3((unsigned)(S / 4 / 256)), 256, 0, stream>>>(x, xb, S);

  // 2. weight transposes + bias concat
  transpose_cast<<<dim3(16, 16), 256, 0, stream>>>(wq, wqkvT,               512, 512);
  transpose_cast<<<dim3(16, 16), 256, 0, stream>>>(wk, wqkvT + 512L * 512,  512, 512);
  transpose_cast<<<dim3(16, 16), 256, 0, stream>>>(wv, wqkvT + 1024L * 512, 512, 512);
  transpose_cast<<<dim3(16, 16), 256, 0, stream>>>(wp, wpT, 512, 512);
  transpose_cast<<<dim3(64, 16), 256, 0, stream>>>(w1, w1T, 512, 2048);
  transpose_cast<<<dim3(16, 64), 256, 0, stream>>>(w2, w2T, 2048, 512);
  concat_bias<<<dim3(6), 256, 0, stream>>>(bq, bk, bv, bqkv);

  // 3. merged QKV GEMM (M=32768, N=1536, K=512), split epilogue:
  //    cols<1024 -> qkb (ldc=1024); cols>=1024 -> vT transposed per batch
  gemm_bt<5, true><<<dim3(12, 256, 1), 256, 0, stream>>>(
      xb, wqkvT, bqkv, qkb, vT, 32768, 1536, 512, 512, 512, 1024, 0, 0, 0, 0.f);

  // 4. attention in 2 chunks of 8 batches
  for (int cgrp = 0; cgrp < 2; cgrp++) {
    const long qoff = (long)cgrp * 8 * 2048 * 1024;
    // E = (q k^T) * 1/sqrt(512)  (M=N=2048, K=512, z=8)
    gemm_bt<2, false><<<dim3(16, 16, 8), 256, 0, stream>>>(
        qkb + qoff, qkb + qoff + 512, nullptr, E, nullptr,
        2048, 2048, 512, 1024, 1024, 2048,
        2048L * 1024, 2048L * 1024, 2048L * 2048, 0.04419417382f);
    // softmax rows
    softmax2048<<<dim3(16384), 256, 0, stream>>>(E);
    // out = P V  (M=2048, N=512, K=2048, z=8)
    gemm_bt<1, false><<<dim3(4, 16, 8), 256, 0, stream>>>(
        E, vT + (long)cgrp * 8 * 512 * 2048, nullptr,
        ob + (long)cgrp * 8 * 2048 * 512, nullptr,
        2048, 512, 2048, 2048, 2048, 512,
        2048L * 2048, 512L * 2048, 2048L * 512, 0.f);
  }

  // 5. proj -> d_out (fp32 scratch)
  gemm_bt<0, true><<<dim3(4, 256, 1), 256, 0, stream>>>(
      ob, wpT, bp, (float*)d_out, nullptr,
      32768, 512, 512, 512, 512, 512, 0, 0, 0, 0.f);

  // 6. x1b = bf16( LN(x + proj) )
  add_ln<false, false, true><<<dim3(32768), 128, 0, stream>>>(
      x, (float*)d_out, g1, be1, nullptr, x1b);

  // 7. FF1: h = gelu(x1 w1 + b1)  (M=32768, N=2048, K=512)
  gemm_bt<3, true><<<dim3(16, 256, 1), 256, 0, stream>>>(
      x1b, w1T, b1, h, nullptr, 32768, 2048, 512, 512, 512, 2048, 0, 0, 0, 0.f);

  // 8. FF2: ff = h w2 + b2 -> d_out (fp32)  (M=32768, N=512, K=2048)
  gemm_bt<0, true><<<dim3(4, 256, 1), 256, 0, stream>>>(
      h, w2T, b2, (float*)d_out, nullptr,
      32768, 512, 2048, 2048, 2048, 512, 0, 0, 0, 0.f);

  // 9. out = LN(x1 + ff), in place on d_out
  add_ln<true, true, false><<<dim3(32768), 128, 0, stream>>>(
      x1b, (float*)d_out, g2, be2, (float*)d_out, nullptr);
}